// Round 10
// baseline (352.076 us; speedup 1.0000x reference)
//
#include <hip/hip_runtime.h>

#define NN 50000
#define NE 600000
#define SCAN_BLOCKS 196  // 196*256 = 50176 >= NN

typedef short v8s __attribute__((ext_vector_type(8)));
typedef float v4f __attribute__((ext_vector_type(4)));

__device__ __forceinline__ float b2f(ushort u) {
    union { unsigned u; float f; } v; v.u = ((unsigned)u) << 16; return v.f;
}
__device__ __forceinline__ ushort f2b(float f) {
    union { float f; unsigned u; } v; v.f = f;
    unsigned r = v.u + 0x7FFFu + ((v.u >> 16) & 1u);  // RNE
    return (ushort)(r >> 16);
}

// ---------- edge-index dtype detection (int32 vs int64 storage) ----------
__global__ __launch_bounds__(256) void detect_idx_kernel(const int* __restrict__ raw,
                                                          int* __restrict__ flag) {
    __shared__ int cnt;
    if (threadIdx.x == 0) cnt = 0;
    __syncthreads();
    int c = 0;
    for (int i = threadIdx.x; i < 2048; i += 256)
        if (raw[2 * i + 1] != 0) c++;
    atomicAdd(&cnt, c);
    __syncthreads();
    if (threadIdx.x == 0) *flag = (cnt > 10) ? 1 : 0;  // 1 => int32 layout
}

// convert + fused degree count (dst half feeds deg atomics)
__global__ __launch_bounds__(256) void convert_idx_kernel(const void* __restrict__ raw,
                                                           const int* __restrict__ flag,
                                                           int* __restrict__ out,
                                                           int* __restrict__ deg, int n) {
    int i = blockIdx.x * 256 + threadIdx.x;
    if (i >= n) return;
    int v;
    if (*flag) v = ((const int*)raw)[i];
    else       v = (int)((const long long*)raw)[i];
    out[i] = v;
    if (i >= NE) atomicAdd(&deg[v], 1);  // dst half
}

// ---------- hierarchical scan: deg[NN] -> rowptr[NN+1], cursor[NN] ----------
__global__ __launch_bounds__(256) void block_sum_kernel(const int* __restrict__ deg,
                                                         int* __restrict__ bsum) {
    const int i = blockIdx.x * 256 + threadIdx.x;
    int v = (i < NN) ? deg[i] : 0;
#pragma unroll
    for (int o = 32; o; o >>= 1) v += __shfl_down(v, o, 64);
    __shared__ int ws[4];
    if ((threadIdx.x & 63) == 0) ws[threadIdx.x >> 6] = v;
    __syncthreads();
    if (threadIdx.x == 0) bsum[blockIdx.x] = ws[0] + ws[1] + ws[2] + ws[3];
}

__global__ __launch_bounds__(256) void scan_sums_kernel(const int* __restrict__ bsum,
                                                         int* __restrict__ boff,
                                                         int* __restrict__ rowptr) {
    __shared__ int tmp[256];
    const int t = threadIdx.x;
    const int v = (t < SCAN_BLOCKS) ? bsum[t] : 0;
    tmp[t] = v;
    __syncthreads();
#pragma unroll
    for (int off = 1; off < 256; off <<= 1) {
        int u = (t >= off) ? tmp[t - off] : 0;
        __syncthreads();
        tmp[t] += u;
        __syncthreads();
    }
    boff[t] = tmp[t] - v;  // exclusive
    if (t == 255) rowptr[NN] = tmp[255];
}

__global__ __launch_bounds__(256) void block_scan_kernel(const int* __restrict__ deg,
                                                          const int* __restrict__ boff,
                                                          int* __restrict__ rowptr,
                                                          int* __restrict__ cursor) {
    const int t = threadIdx.x;
    const int i = blockIdx.x * 256 + t;
    const int lane = t & 63, w = t >> 6;
    const int v = (i < NN) ? deg[i] : 0;
    int s = v;
#pragma unroll
    for (int o = 1; o < 64; o <<= 1) {
        int u = __shfl_up(s, o, 64);
        if (lane >= o) s += u;
    }
    __shared__ int wsum[4];
    if (lane == 63) wsum[w] = s;
    __syncthreads();
    int wpre = 0;
    for (int k = 0; k < w; k++) wpre += wsum[k];
    const int excl = boff[blockIdx.x] + wpre + s - v;
    if (i < NN) {
        rowptr[i] = excl;
        cursor[i] = excl;
    }
}

__global__ __launch_bounds__(256) void fill_csr_kernel(const int* __restrict__ srcIdx,
                                                        const int* __restrict__ dstIdx,
                                                        int* __restrict__ cursor,
                                                        int* __restrict__ csr_src) {
    int e = blockIdx.x * 256 + threadIdx.x;
    if (e >= NE) return;
    int pos = atomicAdd(&cursor[dstIdx[e]], 1);
    csr_src[pos] = srcIdx[e];
}

// ---------- fp32 -> bf16 converters ----------
__global__ __launch_bounds__(256) void cvt_f32_bf16_kernel(const float* __restrict__ in,
                                                            ushort* __restrict__ out, int n4) {
    int i = blockIdx.x * 256 + threadIdx.x;
    if (i >= n4) return;
    const float4 v = *(const float4*)&in[(size_t)i * 4];
    ushort4 o;
    o.x = f2b(v.x); o.y = f2b(v.y); o.z = f2b(v.z); o.w = f2b(v.w);
    *(ushort4*)&out[(size_t)i * 4] = o;
}

// out[n*K+k] = bf16(in[k*N+n])  (natural transpose; stage-1 weights)
__global__ __launch_bounds__(256) void transpose_cvt_kernel(const float* __restrict__ in,
                                                             ushort* __restrict__ out,
                                                             int K, int N) {
    int idx = blockIdx.x * 256 + threadIdx.x;
    if (idx >= K * N) return;
    int n = idx / K, k = idx - n * K;
    out[idx] = f2b(in[(size_t)k * N + n]);
}

// stage-2 weights: transpose + K-permute pi(s,kq,j) = 32s + (j>=4?16:0) + kq*4 + (j&3)
// so that stage-1's register-resident m (lane holds hid {16n+kq*4+r}) feeds the
// MFMA B-operand with NO cross-lane traffic. in: [256][N] fp32; out: [N][256] bf16.
__global__ __launch_bounds__(256) void permute_cvt_kernel(const float* __restrict__ in,
                                                           ushort* __restrict__ out, int N) {
    int idx = blockIdx.x * 256 + threadIdx.x;
    if (idx >= 256 * N) return;
    int n = idx >> 8, kk = idx & 255;
    int s = kk >> 5, r5 = kk & 31, kq = r5 >> 3, j = r5 & 7;
    int pi = s * 32 + ((j & 4) ? 16 : 0) + kq * 4 + (j & 3);
    out[idx] = f2b(in[(size_t)pi * N + n]);
}

// ---------- gather-aggregate (bf16 in/out, fp32 accum) ----------
template <int D>
__global__ __launch_bounds__(256) void aggregate_bf16_kernel(const ushort* __restrict__ feat,
                                                              ushort* __restrict__ z,
                                                              const int* __restrict__ rowptr,
                                                              const int* __restrict__ csr_src) {
    const int node = blockIdx.x * 4 + (threadIdx.x >> 6);
    const int lane = threadIdx.x & 63;
    if (node >= NN) return;
    const int rbeg = rowptr[node];
    const int rend = rowptr[node + 1];

    if (D == 256) {
        const size_t base = (size_t)node * 256 + lane * 4;
        uint2 sv = *(const uint2*)&feat[base];
        float a0 = b2f((ushort)sv.x), a1 = b2f((ushort)(sv.x >> 16));
        float a2 = b2f((ushort)sv.y), a3 = b2f((ushort)(sv.y >> 16));
        int j = rbeg;
        for (; j + 3 < rend; j += 4) {
            const int s0 = csr_src[j], s1 = csr_src[j + 1];
            const int s2 = csr_src[j + 2], s3 = csr_src[j + 3];
            const uint2 v0 = *(const uint2*)&feat[(size_t)s0 * 256 + lane * 4];
            const uint2 v1 = *(const uint2*)&feat[(size_t)s1 * 256 + lane * 4];
            const uint2 v2 = *(const uint2*)&feat[(size_t)s2 * 256 + lane * 4];
            const uint2 v3 = *(const uint2*)&feat[(size_t)s3 * 256 + lane * 4];
            a0 += b2f((ushort)v0.x) + b2f((ushort)v1.x) + b2f((ushort)v2.x) + b2f((ushort)v3.x);
            a1 += b2f((ushort)(v0.x >> 16)) + b2f((ushort)(v1.x >> 16)) + b2f((ushort)(v2.x >> 16)) + b2f((ushort)(v3.x >> 16));
            a2 += b2f((ushort)v0.y) + b2f((ushort)v1.y) + b2f((ushort)v2.y) + b2f((ushort)v3.y);
            a3 += b2f((ushort)(v0.y >> 16)) + b2f((ushort)(v1.y >> 16)) + b2f((ushort)(v2.y >> 16)) + b2f((ushort)(v3.y >> 16));
        }
        for (; j < rend; j++) {
            const uint2 v = *(const uint2*)&feat[(size_t)csr_src[j] * 256 + lane * 4];
            a0 += b2f((ushort)v.x); a1 += b2f((ushort)(v.x >> 16));
            a2 += b2f((ushort)v.y); a3 += b2f((ushort)(v.y >> 16));
        }
        uint2 o;
        o.x = (uint)f2b(a0) | ((uint)f2b(a1) << 16);
        o.y = (uint)f2b(a2) | ((uint)f2b(a3) << 16);
        *(uint2*)&z[base] = o;
    } else {  // D == 128
        const size_t base = (size_t)node * 128 + lane * 2;
        uint sv = *(const uint*)&feat[base];
        float a0 = b2f((ushort)sv), a1 = b2f((ushort)(sv >> 16));
        int j = rbeg;
        for (; j + 3 < rend; j += 4) {
            const int s0 = csr_src[j], s1 = csr_src[j + 1];
            const int s2 = csr_src[j + 2], s3 = csr_src[j + 3];
            const uint v0 = *(const uint*)&feat[(size_t)s0 * 128 + lane * 2];
            const uint v1 = *(const uint*)&feat[(size_t)s1 * 128 + lane * 2];
            const uint v2 = *(const uint*)&feat[(size_t)s2 * 128 + lane * 2];
            const uint v3 = *(const uint*)&feat[(size_t)s3 * 128 + lane * 2];
            a0 += b2f((ushort)v0) + b2f((ushort)v1) + b2f((ushort)v2) + b2f((ushort)v3);
            a1 += b2f((ushort)(v0 >> 16)) + b2f((ushort)(v1 >> 16)) + b2f((ushort)(v2 >> 16)) + b2f((ushort)(v3 >> 16));
        }
        for (; j < rend; j++) {
            const uint v = *(const uint*)&feat[(size_t)csr_src[j] * 128 + lane * 2];
            a0 += b2f((ushort)v); a1 += b2f((ushort)(v >> 16));
        }
        *(uint*)&z[base] = (uint)f2b(a0) | ((uint)f2b(a1) << 16);
    }
}

// ---------- fused 2-layer MLP v3: LDS-free, barrier-free, per-wave ----------
// Each wave owns 16 nodes (node = base + l15), fully independent. Swapped MFMA:
//   stage1: acc1[n] = mfma(W1frag, zfrag)  -> D col=l15=node, row=kq*4+r=hid%16
// so lane (kq,l15) ends with m[node l15][hid 16n+kq*4+r] in registers. These pack
// (bias+relu+f2b) into mpk[8] v8s which IS the stage-2 B-fragment under the
// k-permutation baked into W2p by permute_cvt_kernel. Zero LDS, zero barriers.
// A/B frag: row/col=l&15, k=(l>>4)*8+j; D: col=l&15, row=(l>>4)*4+reg (m89/m91).
template <int K1, bool HEAD>
__global__ __launch_bounds__(256) void fused_mlp_kernel(const ushort* __restrict__ Z,
                                                         const ushort* __restrict__ W1t,
                                                         const float* __restrict__ b1,
                                                         const ushort* __restrict__ W2p,
                                                         const float* __restrict__ b2,
                                                         void* __restrict__ outp, int M) {
    constexpr int S1 = K1 / 32;
    const int lane = threadIdx.x & 63;
    const int wv = threadIdx.x >> 6;
    const int l15 = lane & 15;
    const int kq = lane >> 4;
    const int node = blockIdx.x * 64 + wv * 16 + l15;
    const int zr = min(node, M - 1);

    const ushort* zb  = Z   + (size_t)zr  * K1 + kq * 8;
    const ushort* w1b = W1t + (size_t)l15 * K1 + kq * 8;

    // ---- stage 1: m = relu(z @ W1 + b1), swapped operands ----
    v4f acc1[16];
#pragma unroll
    for (int n = 0; n < 16; n++) acc1[n] = (v4f){0.f, 0.f, 0.f, 0.f};
#pragma unroll
    for (int s = 0; s < S1; s++) {
        const v8s zf = *(const v8s*)(zb + s * 32);
#pragma unroll
        for (int n = 0; n < 16; n++) {
            const v8s wf = *(const v8s*)(w1b + (size_t)n * 16 * K1 + s * 32);
            acc1[n] = __builtin_amdgcn_mfma_f32_16x16x32_bf16(wf, zf, acc1[n], 0, 0, 0);
        }
    }

    // ---- pack: bias + relu + f2b -> stage-2 B-fragments (register-only) ----
    v8s mpk[8];
#pragma unroll
    for (int n = 0; n < 16; n++) {
        const float4 bv = *(const float4*)&b1[n * 16 + kq * 4];
        const int s = n >> 1, h = (n & 1) * 4;
        mpk[s][h + 0] = (short)f2b(fmaxf(acc1[n][0] + bv.x, 0.f));
        mpk[s][h + 1] = (short)f2b(fmaxf(acc1[n][1] + bv.y, 0.f));
        mpk[s][h + 2] = (short)f2b(fmaxf(acc1[n][2] + bv.z, 0.f));
        mpk[s][h + 3] = (short)f2b(fmaxf(acc1[n][3] + bv.w, 0.f));
    }

    const ushort* w2b_ = W2p + (size_t)l15 * 256 + kq * 8;

    if constexpr (!HEAD) {
        // ---- stage 2: C = relu(m @ W2 + b2), 256 cols ----
        v4f acc2[16];
#pragma unroll
        for (int n = 0; n < 16; n++) acc2[n] = (v4f){0.f, 0.f, 0.f, 0.f};
#pragma unroll
        for (int s = 0; s < 8; s++) {
#pragma unroll
            for (int n = 0; n < 16; n++) {
                const v8s wf = *(const v8s*)(w2b_ + (size_t)n * 16 * 256 + s * 32);
                acc2[n] = __builtin_amdgcn_mfma_f32_16x16x32_bf16(wf, mpk[s], acc2[n], 0, 0, 0);
            }
        }
        if (node < M) {
            ushort* C = (ushort*)outp;
#pragma unroll
            for (int n = 0; n < 16; n++) {
                const float4 bv = *(const float4*)&b2[n * 16 + kq * 4];
                uint2 st;
                st.x = (uint)f2b(fmaxf(acc2[n][0] + bv.x, 0.f)) |
                       ((uint)f2b(fmaxf(acc2[n][1] + bv.y, 0.f)) << 16);
                st.y = (uint)f2b(fmaxf(acc2[n][2] + bv.z, 0.f)) |
                       ((uint)f2b(fmaxf(acc2[n][3] + bv.w, 0.f)) << 16);
                *(uint2*)&C[(size_t)node * 256 + n * 16 + kq * 4] = st;
            }
        }
    } else {
        // ---- stage 2 head: o = m @ W2b + b2 (16 cols) + log_softmax ----
        v4f h = (v4f){0.f, 0.f, 0.f, 0.f};
#pragma unroll
        for (int s = 0; s < 8; s++) {
            const v8s wf = *(const v8s*)(w2b_ + s * 32);
            h = __builtin_amdgcn_mfma_f32_16x16x32_bf16(wf, mpk[s], h, 0, 0, 0);
        }
        const float4 bv = *(const float4*)&b2[kq * 4];
        const float v0 = h[0] + bv.x, v1 = h[1] + bv.y, v2 = h[2] + bv.z, v3 = h[3] + bv.w;
        float mx = fmaxf(fmaxf(v0, v1), fmaxf(v2, v3));
        mx = fmaxf(mx, __shfl_xor(mx, 16));
        mx = fmaxf(mx, __shfl_xor(mx, 32));
        float sl = expf(v0 - mx) + expf(v1 - mx) + expf(v2 - mx) + expf(v3 - mx);
        sl += __shfl_xor(sl, 16);
        sl += __shfl_xor(sl, 32);
        const float ls = logf(sl);
        if (node < M) {
            float4 o;
            o.x = (v0 - mx) - ls; o.y = (v1 - mx) - ls;
            o.z = (v2 - mx) - ls; o.w = (v3 - mx) - ls;
            *(float4*)&((float*)outp)[(size_t)node * 16 + kq * 4] = o;
        }
    }
}

extern "C" void kernel_launch(void* const* d_in, const int* in_sizes, int n_in,
                              void* d_out, int out_size, void* d_ws, size_t ws_size,
                              hipStream_t stream) {
    (void)in_sizes; (void)n_in; (void)out_size; (void)ws_size;
    const float* x   = (const float*)d_in[0];
    const void*  ei  = d_in[1];
    const float* w1a = (const float*)d_in[2];
    const float* b1a = (const float*)d_in[3];
    const float* w2a = (const float*)d_in[4];
    const float* b2a = (const float*)d_in[5];
    const float* w1b = (const float*)d_in[6];
    const float* b1b = (const float*)d_in[7];
    const float* w2b = (const float*)d_in[8];
    const float* b2b = (const float*)d_in[9];
    float* out = (float*)d_out;

    // ws layout (ushort region first, then ints)
    ushort* XB   = (ushort*)d_ws;                 // [NN][128] bf16: x
    ushort* Z1   = XB + (size_t)NN * 128;         // [NN][128] bf16: z1
    ushort* H1   = Z1 + (size_t)NN * 128;         // [NN][256] bf16: h1
    ushort* Z2   = H1 + (size_t)NN * 256;         // [NN][256] bf16: z2
    ushort* Wt1a = Z2 + (size_t)NN * 256;         // [256][128] natural^T
    ushort* W2pa = Wt1a + 256 * 128;              // [256][256] permuted
    ushort* Wt1b = W2pa + 256 * 256;              // [256][256] natural^T
    ushort* W2bp = Wt1b + 256 * 256;              // [16][256]  permuted
    int* idx     = (int*)(W2bp + 16 * 256);       // 2*NE
    int* flag    = idx + 2 * NE;
    int* deg     = flag + 1;                      // NN
    int* rowptr  = deg + NN;                      // NN+1
    int* cursor  = rowptr + NN + 1;               // NN
    int* csr_src = cursor + NN;                   // NE
    int* bsum    = csr_src + NE;                  // SCAN_BLOCKS
    int* boff    = bsum + SCAN_BLOCKS;            // 256

    // ---- edge index normalize + CSR ----
    detect_idx_kernel<<<1, 256, 0, stream>>>((const int*)ei, flag);
    hipMemsetAsync(deg, 0, NN * sizeof(int), stream);
    convert_idx_kernel<<<(2 * NE + 255) / 256, 256, 0, stream>>>(ei, flag, idx, deg, 2 * NE);
    const int* srcI = idx;
    const int* dstI = idx + NE;
    block_sum_kernel<<<SCAN_BLOCKS, 256, 0, stream>>>(deg, bsum);
    scan_sums_kernel<<<1, 256, 0, stream>>>(bsum, boff, rowptr);
    block_scan_kernel<<<SCAN_BLOCKS, 256, 0, stream>>>(deg, boff, rowptr, cursor);
    fill_csr_kernel<<<(NE + 255) / 256, 256, 0, stream>>>(srcI, dstI, cursor, csr_src);

    // ---- weight prep ----
    cvt_f32_bf16_kernel<<<(NN * 128 / 4 + 255) / 256, 256, 0, stream>>>(x, XB, NN * 128 / 4);
    transpose_cvt_kernel<<<(128 * 256 + 255) / 256, 256, 0, stream>>>(w1a, Wt1a, 128, 256);
    permute_cvt_kernel<<<(256 * 256 + 255) / 256, 256, 0, stream>>>(w2a, W2pa, 256);
    transpose_cvt_kernel<<<(256 * 256 + 255) / 256, 256, 0, stream>>>(w1b, Wt1b, 256, 256);
    permute_cvt_kernel<<<(256 * 16 + 255) / 256, 256, 0, stream>>>(w2b, W2bp, 16);

    const int aggBlocks = (NN + 3) / 4;
    const int mlpBlocks = (NN + 63) / 64;  // 64 nodes/block = 4 indep waves x 16

    // ---- conv1: aggregate + fused MLP (z1 -> h1) ----
    aggregate_bf16_kernel<128><<<aggBlocks, 256, 0, stream>>>(XB, Z1, rowptr, csr_src);
    fused_mlp_kernel<128, false><<<mlpBlocks, 256, 0, stream>>>(Z1, Wt1a, b1a, W2pa, b2a, H1, NN);

    // ---- conv2: aggregate + fused MLP + head (z2 -> out) ----
    aggregate_bf16_kernel<256><<<aggBlocks, 256, 0, stream>>>(H1, Z2, rowptr, csr_src);
    fused_mlp_kernel<256, true><<<mlpBlocks, 256, 0, stream>>>(Z2, Wt1b, b1b, W2bp, b2b, out, NN);
}

// Round 11
// 259.667 us; speedup vs baseline: 1.3559x; 1.3559x over previous
//
#include <hip/hip_runtime.h>

#define NN 50000
#define NE 600000
#define SCAN_BLOCKS 196  // 196*256 = 50176 >= NN

typedef short v8s __attribute__((ext_vector_type(8)));
typedef float v4f __attribute__((ext_vector_type(4)));

#define LAW 40    // lA row stride in shorts: 32 data + 8 pad (80B)
#define MTW 264   // mT row stride in shorts: 256 data + 8 pad (528B)

__device__ __forceinline__ float b2f(ushort u) {
    union { unsigned u; float f; } v; v.u = ((unsigned)u) << 16; return v.f;
}
__device__ __forceinline__ ushort f2b(float f) {
    union { float f; unsigned u; } v; v.f = f;
    unsigned r = v.u + 0x7FFFu + ((v.u >> 16) & 1u);  // RNE
    return (ushort)(r >> 16);
}

// ---------- edge-index dtype detection (int32 vs int64 storage) ----------
__global__ __launch_bounds__(256) void detect_idx_kernel(const int* __restrict__ raw,
                                                          int* __restrict__ flag) {
    __shared__ int cnt;
    if (threadIdx.x == 0) cnt = 0;
    __syncthreads();
    int c = 0;
    for (int i = threadIdx.x; i < 2048; i += 256)
        if (raw[2 * i + 1] != 0) c++;
    atomicAdd(&cnt, c);
    __syncthreads();
    if (threadIdx.x == 0) *flag = (cnt > 10) ? 1 : 0;  // 1 => int32 layout
}

// convert + fused degree count (dst half feeds deg atomics)
__global__ __launch_bounds__(256) void convert_idx_kernel(const void* __restrict__ raw,
                                                           const int* __restrict__ flag,
                                                           int* __restrict__ out,
                                                           int* __restrict__ deg, int n) {
    int i = blockIdx.x * 256 + threadIdx.x;
    if (i >= n) return;
    int v;
    if (*flag) v = ((const int*)raw)[i];
    else       v = (int)((const long long*)raw)[i];
    out[i] = v;
    if (i >= NE) atomicAdd(&deg[v], 1);  // dst half
}

// ---------- hierarchical scan: deg[NN] -> rowptr[NN+1], cursor[NN] ----------
__global__ __launch_bounds__(256) void block_sum_kernel(const int* __restrict__ deg,
                                                         int* __restrict__ bsum) {
    const int i = blockIdx.x * 256 + threadIdx.x;
    int v = (i < NN) ? deg[i] : 0;
#pragma unroll
    for (int o = 32; o; o >>= 1) v += __shfl_down(v, o, 64);
    __shared__ int ws[4];
    if ((threadIdx.x & 63) == 0) ws[threadIdx.x >> 6] = v;
    __syncthreads();
    if (threadIdx.x == 0) bsum[blockIdx.x] = ws[0] + ws[1] + ws[2] + ws[3];
}

__global__ __launch_bounds__(256) void scan_sums_kernel(const int* __restrict__ bsum,
                                                         int* __restrict__ boff,
                                                         int* __restrict__ rowptr) {
    __shared__ int tmp[256];
    const int t = threadIdx.x;
    const int v = (t < SCAN_BLOCKS) ? bsum[t] : 0;
    tmp[t] = v;
    __syncthreads();
#pragma unroll
    for (int off = 1; off < 256; off <<= 1) {
        int u = (t >= off) ? tmp[t - off] : 0;
        __syncthreads();
        tmp[t] += u;
        __syncthreads();
    }
    boff[t] = tmp[t] - v;  // exclusive
    if (t == 255) rowptr[NN] = tmp[255];
}

__global__ __launch_bounds__(256) void block_scan_kernel(const int* __restrict__ deg,
                                                          const int* __restrict__ boff,
                                                          int* __restrict__ rowptr,
                                                          int* __restrict__ cursor) {
    const int t = threadIdx.x;
    const int i = blockIdx.x * 256 + t;
    const int lane = t & 63, w = t >> 6;
    const int v = (i < NN) ? deg[i] : 0;
    int s = v;
#pragma unroll
    for (int o = 1; o < 64; o <<= 1) {
        int u = __shfl_up(s, o, 64);
        if (lane >= o) s += u;
    }
    __shared__ int wsum[4];
    if (lane == 63) wsum[w] = s;
    __syncthreads();
    int wpre = 0;
    for (int k = 0; k < w; k++) wpre += wsum[k];
    const int excl = boff[blockIdx.x] + wpre + s - v;
    if (i < NN) {
        rowptr[i] = excl;
        cursor[i] = excl;
    }
}

__global__ __launch_bounds__(256) void fill_csr_kernel(const int* __restrict__ srcIdx,
                                                        const int* __restrict__ dstIdx,
                                                        int* __restrict__ cursor,
                                                        int* __restrict__ csr_src) {
    int e = blockIdx.x * 256 + threadIdx.x;
    if (e >= NE) return;
    int pos = atomicAdd(&cursor[dstIdx[e]], 1);
    csr_src[pos] = srcIdx[e];
}

// ---------- fp32 -> bf16 converters ----------
__global__ __launch_bounds__(256) void cvt_f32_bf16_kernel(const float* __restrict__ in,
                                                            ushort* __restrict__ out, int n4) {
    int i = blockIdx.x * 256 + threadIdx.x;
    if (i >= n4) return;
    const float4 v = *(const float4*)&in[(size_t)i * 4];
    ushort4 o;
    o.x = f2b(v.x); o.y = f2b(v.y); o.z = f2b(v.z); o.w = f2b(v.w);
    *(ushort4*)&out[(size_t)i * 4] = o;
}

// out[n*K+k] = bf16(in[k*N+n])  (weights: tiny, once per call)
__global__ __launch_bounds__(256) void transpose_cvt_kernel(const float* __restrict__ in,
                                                             ushort* __restrict__ out,
                                                             int K, int N) {
    int idx = blockIdx.x * 256 + threadIdx.x;
    if (idx >= K * N) return;
    int n = idx / K, k = idx - n * K;
    out[idx] = f2b(in[(size_t)k * N + n]);
}

// ---------- gather-aggregate (bf16 in/out, fp32 accum) ----------
template <int D>
__global__ __launch_bounds__(256) void aggregate_bf16_kernel(const ushort* __restrict__ feat,
                                                              ushort* __restrict__ z,
                                                              const int* __restrict__ rowptr,
                                                              const int* __restrict__ csr_src) {
    const int node = blockIdx.x * 4 + (threadIdx.x >> 6);
    const int lane = threadIdx.x & 63;
    if (node >= NN) return;
    const int rbeg = rowptr[node];
    const int rend = rowptr[node + 1];

    if (D == 256) {
        const size_t base = (size_t)node * 256 + lane * 4;
        uint2 sv = *(const uint2*)&feat[base];
        float a0 = b2f((ushort)sv.x), a1 = b2f((ushort)(sv.x >> 16));
        float a2 = b2f((ushort)sv.y), a3 = b2f((ushort)(sv.y >> 16));
        int j = rbeg;
        for (; j + 3 < rend; j += 4) {
            const int s0 = csr_src[j], s1 = csr_src[j + 1];
            const int s2 = csr_src[j + 2], s3 = csr_src[j + 3];
            const uint2 v0 = *(const uint2*)&feat[(size_t)s0 * 256 + lane * 4];
            const uint2 v1 = *(const uint2*)&feat[(size_t)s1 * 256 + lane * 4];
            const uint2 v2 = *(const uint2*)&feat[(size_t)s2 * 256 + lane * 4];
            const uint2 v3 = *(const uint2*)&feat[(size_t)s3 * 256 + lane * 4];
            a0 += b2f((ushort)v0.x) + b2f((ushort)v1.x) + b2f((ushort)v2.x) + b2f((ushort)v3.x);
            a1 += b2f((ushort)(v0.x >> 16)) + b2f((ushort)(v1.x >> 16)) + b2f((ushort)(v2.x >> 16)) + b2f((ushort)(v3.x >> 16));
            a2 += b2f((ushort)v0.y) + b2f((ushort)v1.y) + b2f((ushort)v2.y) + b2f((ushort)v3.y);
            a3 += b2f((ushort)(v0.y >> 16)) + b2f((ushort)(v1.y >> 16)) + b2f((ushort)(v2.y >> 16)) + b2f((ushort)(v3.y >> 16));
        }
        for (; j < rend; j++) {
            const uint2 v = *(const uint2*)&feat[(size_t)csr_src[j] * 256 + lane * 4];
            a0 += b2f((ushort)v.x); a1 += b2f((ushort)(v.x >> 16));
            a2 += b2f((ushort)v.y); a3 += b2f((ushort)(v.y >> 16));
        }
        uint2 o;
        o.x = (uint)f2b(a0) | ((uint)f2b(a1) << 16);
        o.y = (uint)f2b(a2) | ((uint)f2b(a3) << 16);
        *(uint2*)&z[base] = o;
    } else {  // D == 128
        const size_t base = (size_t)node * 128 + lane * 2;
        uint sv = *(const uint*)&feat[base];
        float a0 = b2f((ushort)sv), a1 = b2f((ushort)(sv >> 16));
        int j = rbeg;
        for (; j + 3 < rend; j += 4) {
            const int s0 = csr_src[j], s1 = csr_src[j + 1];
            const int s2 = csr_src[j + 2], s3 = csr_src[j + 3];
            const uint v0 = *(const uint*)&feat[(size_t)s0 * 128 + lane * 2];
            const uint v1 = *(const uint*)&feat[(size_t)s1 * 128 + lane * 2];
            const uint v2 = *(const uint*)&feat[(size_t)s2 * 128 + lane * 2];
            const uint v3 = *(const uint*)&feat[(size_t)s3 * 128 + lane * 2];
            a0 += b2f((ushort)v0) + b2f((ushort)v1) + b2f((ushort)v2) + b2f((ushort)v3);
            a1 += b2f((ushort)(v0 >> 16)) + b2f((ushort)(v1 >> 16)) + b2f((ushort)(v2 >> 16)) + b2f((ushort)(v3 >> 16));
        }
        for (; j < rend; j++) {
            const uint v = *(const uint*)&feat[(size_t)csr_src[j] * 128 + lane * 2];
            a0 += b2f((ushort)v); a1 += b2f((ushort)(v >> 16));
        }
        *(uint*)&z[base] = (uint)f2b(a0) | ((uint)f2b(a1) << 16);
    }
}

// ---------- fused 2-layer MLP v4: BM=32, high-occupancy ----------
// Block: 32 rows, 256 threads (4 waves); wave wv owns cols wv*64..+63.
// LDS: dbuf A k-tile (2x2.5KB) + mT (16.5KB) = 22KB -> ~7 blocks/CU; grid 1563.
// W1/W2 stay as per-lane register fragments from L2 (block-shared addresses,
// no per-wave traffic amplification - round-10 lesson).
// Frag layouts (m89/m91): A row=l&15, k=(l>>4)*8+j; B col=l&15 same k;
// D col=l&15, row=(l>>4)*4+reg.
template <int K1, bool HEAD>
__global__ __launch_bounds__(256) void fused_mlp_kernel(const ushort* __restrict__ A,
                                                         const ushort* __restrict__ W1t,
                                                         const float* __restrict__ b1,
                                                         const ushort* __restrict__ W2t,
                                                         const float* __restrict__ b2,
                                                         void* __restrict__ outp, int M) {
    constexpr int S1 = K1 / 32;         // stage-1 k-steps
    __shared__ ushort lA[2][32 * LAW];  // 2 x 2.5 KB
    __shared__ ushort mT[32 * MTW];     // 16.5 KB
    const int tid = threadIdx.x;
    const int lane = tid & 63;
    const int wv = tid >> 6;
    const int row0 = blockIdx.x * 32;
    const int l15 = lane & 15;
    const int kq = lane >> 4;                     // 0..3
    const int ar = tid >> 3, ak = (tid & 7) * 4;  // A staging: row 0..31, 8B chunk

    const bool aok = (row0 + ar) < M;
    const ushort* Arow = A + (size_t)(row0 + ar) * K1 + ak;
    const ushort* w1b = W1t + (size_t)(wv * 64 + l15) * K1 + kq * 8;

    v4f acc[2][4];
#pragma unroll
    for (int m = 0; m < 2; m++)
#pragma unroll
        for (int n = 0; n < 4; n++) acc[m][n] = (v4f){0.f, 0.f, 0.f, 0.f};

    // prologue: stage k-step 0
    uint2 av = {0u, 0u};
    if (aok) av = *(const uint2*)Arow;
    *(uint2*)&lA[0][ar * LAW + ak] = av;

    // ---- stage 1: m = relu(A @ W1 + b1) ----
#pragma unroll
    for (int s = 0; s < S1; s++) {
        __syncthreads();
        uint2 avn = {0u, 0u};
        if (s + 1 < S1 && aok) avn = *(const uint2*)(Arow + (s + 1) * 32);
        v8s af[2];
#pragma unroll
        for (int m = 0; m < 2; m++)
            af[m] = *(const v8s*)&lA[s & 1][(m * 16 + l15) * LAW + kq * 8];
#pragma unroll
        for (int n = 0; n < 4; n++) {
            const v8s wf = *(const v8s*)(w1b + (size_t)n * 16 * K1 + s * 32);
            acc[0][n] = __builtin_amdgcn_mfma_f32_16x16x32_bf16(af[0], wf, acc[0][n], 0, 0, 0);
            acc[1][n] = __builtin_amdgcn_mfma_f32_16x16x32_bf16(af[1], wf, acc[1][n], 0, 0, 0);
        }
        if (s + 1 < S1) *(uint2*)&lA[(s + 1) & 1][ar * LAW + ak] = avn;
    }

    // ---- stage-1 epilogue: bias + relu -> mT (bf16) ----
#pragma unroll
    for (int n = 0; n < 4; n++) {
        const int gc = wv * 64 + n * 16 + l15;
        const float bv = b1[gc];
#pragma unroll
        for (int m = 0; m < 2; m++)
#pragma unroll
            for (int r = 0; r < 4; r++)
                mT[(m * 16 + kq * 4 + r) * MTW + gc] = f2b(fmaxf(acc[m][n][r] + bv, 0.f));
    }
    __syncthreads();  // mT ready; last barrier

    if constexpr (!HEAD) {
        // ---- stage 2: C = relu(m @ W2 + b2), 256 cols, barrier-free ----
#pragma unroll
        for (int m = 0; m < 2; m++)
#pragma unroll
            for (int n = 0; n < 4; n++) acc[m][n] = (v4f){0.f, 0.f, 0.f, 0.f};
        const ushort* w2b_ = W2t + (size_t)(wv * 64 + l15) * 256 + kq * 8;
#pragma unroll
        for (int s = 0; s < 8; s++) {
            v8s af2[2];
#pragma unroll
            for (int m = 0; m < 2; m++)
                af2[m] = *(const v8s*)&mT[(m * 16 + l15) * MTW + s * 32 + kq * 8];
#pragma unroll
            for (int n = 0; n < 4; n++) {
                const v8s wf = *(const v8s*)(w2b_ + (size_t)n * 16 * 256 + s * 32);
                acc[0][n] = __builtin_amdgcn_mfma_f32_16x16x32_bf16(af2[0], wf, acc[0][n], 0, 0, 0);
                acc[1][n] = __builtin_amdgcn_mfma_f32_16x16x32_bf16(af2[1], wf, acc[1][n], 0, 0, 0);
            }
        }
        ushort* C = (ushort*)outp;
#pragma unroll
        for (int n = 0; n < 4; n++) {
            const int gc = wv * 64 + n * 16 + l15;
            const float bv = b2[gc];
#pragma unroll
            for (int m = 0; m < 2; m++) {
                const int rbase = row0 + m * 16 + kq * 4;
#pragma unroll
                for (int r = 0; r < 4; r++) {
                    const int gr = rbase + r;
                    if (gr < M) C[(size_t)gr * 256 + gc] = f2b(fmaxf(acc[0][0][0] * 0.f + acc[m][n][r] + bv, 0.f));
                }
            }
        }
    } else {
        // ---- stage 2 head: waves 0,1 compute rows wv*16..+15; o=m@W2b+b2, log_softmax ----
        if (wv < 2) {
            v4f h = (v4f){0.f, 0.f, 0.f, 0.f};
            const ushort* w2b_ = W2t + (size_t)l15 * 256 + kq * 8;
#pragma unroll
            for (int s = 0; s < 8; s++) {
                const v8s af2 = *(const v8s*)&mT[(wv * 16 + l15) * MTW + s * 32 + kq * 8];
                const v8s wf = *(const v8s*)(w2b_ + s * 32);
                h = __builtin_amdgcn_mfma_f32_16x16x32_bf16(af2, wf, h, 0, 0, 0);
            }
            float* O = (float*)outp;
            const float bv = b2[l15];
#pragma unroll
            for (int r = 0; r < 4; r++) {
                const float v = h[r] + bv;
                float mx = v;
#pragma unroll
                for (int o = 8; o; o >>= 1) mx = fmaxf(mx, __shfl_xor(mx, o, 16));
                const float e = expf(v - mx);
                float sl = e;
#pragma unroll
                for (int o = 8; o; o >>= 1) sl += __shfl_xor(sl, o, 16);
                const int grow = row0 + wv * 16 + kq * 4 + r;
                if (grow < M) O[(size_t)grow * 16 + l15] = (v - mx) - logf(sl);
            }
        }
    }
}

extern "C" void kernel_launch(void* const* d_in, const int* in_sizes, int n_in,
                              void* d_out, int out_size, void* d_ws, size_t ws_size,
                              hipStream_t stream) {
    (void)in_sizes; (void)n_in; (void)out_size; (void)ws_size;
    const float* x   = (const float*)d_in[0];
    const void*  ei  = d_in[1];
    const float* w1a = (const float*)d_in[2];
    const float* b1a = (const float*)d_in[3];
    const float* w2a = (const float*)d_in[4];
    const float* b2a = (const float*)d_in[5];
    const float* w1b = (const float*)d_in[6];
    const float* b1b = (const float*)d_in[7];
    const float* w2b = (const float*)d_in[8];
    const float* b2b = (const float*)d_in[9];
    float* out = (float*)d_out;

    // ws layout (ushort region first, then ints)
    ushort* XB   = (ushort*)d_ws;                 // [NN][128] bf16: x
    ushort* Z1   = XB + (size_t)NN * 128;         // [NN][128] bf16: z1
    ushort* H1   = Z1 + (size_t)NN * 128;         // [NN][256] bf16: h1
    ushort* Z2   = H1 + (size_t)NN * 256;         // [NN][256] bf16: z2
    ushort* Wt1a = Z2 + (size_t)NN * 256;         // [256][128]
    ushort* Wt2a = Wt1a + 256 * 128;              // [256][256]
    ushort* Wt1b = Wt2a + 256 * 256;              // [256][256]
    ushort* Wt2b = Wt1b + 256 * 256;              // [16][256]
    int* idx     = (int*)(Wt2b + 16 * 256);       // 2*NE
    int* flag    = idx + 2 * NE;
    int* deg     = flag + 1;                      // NN
    int* rowptr  = deg + NN;                      // NN+1
    int* cursor  = rowptr + NN + 1;               // NN
    int* csr_src = cursor + NN;                   // NE
    int* bsum    = csr_src + NE;                  // SCAN_BLOCKS
    int* boff    = bsum + SCAN_BLOCKS;            // 256

    // ---- edge index normalize + CSR ----
    detect_idx_kernel<<<1, 256, 0, stream>>>((const int*)ei, flag);
    hipMemsetAsync(deg, 0, NN * sizeof(int), stream);
    convert_idx_kernel<<<(2 * NE + 255) / 256, 256, 0, stream>>>(ei, flag, idx, deg, 2 * NE);
    const int* srcI = idx;
    const int* dstI = idx + NE;
    block_sum_kernel<<<SCAN_BLOCKS, 256, 0, stream>>>(deg, bsum);
    scan_sums_kernel<<<1, 256, 0, stream>>>(bsum, boff, rowptr);
    block_scan_kernel<<<SCAN_BLOCKS, 256, 0, stream>>>(deg, boff, rowptr, cursor);
    fill_csr_kernel<<<(NE + 255) / 256, 256, 0, stream>>>(srcI, dstI, cursor, csr_src);

    // ---- bf16 conversions ----
    cvt_f32_bf16_kernel<<<(NN * 128 / 4 + 255) / 256, 256, 0, stream>>>(x, XB, NN * 128 / 4);
    transpose_cvt_kernel<<<(128 * 256 + 255) / 256, 256, 0, stream>>>(w1a, Wt1a, 128, 256);
    transpose_cvt_kernel<<<(256 * 256 + 255) / 256, 256, 0, stream>>>(w2a, Wt2a, 256, 256);
    transpose_cvt_kernel<<<(256 * 256 + 255) / 256, 256, 0, stream>>>(w1b, Wt1b, 256, 256);
    transpose_cvt_kernel<<<(256 * 16 + 255) / 256, 256, 0, stream>>>(w2b, Wt2b, 256, 16);

    const int aggBlocks = (NN + 3) / 4;
    const int mlpBlocks = (NN + 31) / 32;  // BM=32 -> 1563 blocks

    // ---- conv1: aggregate + fused MLP (z1 -> h1) ----
    aggregate_bf16_kernel<128><<<aggBlocks, 256, 0, stream>>>(XB, Z1, rowptr, csr_src);
    fused_mlp_kernel<128, false><<<mlpBlocks, 256, 0, stream>>>(Z1, Wt1a, b1a, Wt2a, b2a, H1, NN);

    // ---- conv2: aggregate + fused MLP + head (z2 -> out) ----
    aggregate_bf16_kernel<256><<<aggBlocks, 256, 0, stream>>>(H1, Z2, rowptr, csr_src);
    fused_mlp_kernel<256, true><<<mlpBlocks, 256, 0, stream>>>(Z2, Wt1b, b1b, Wt2b, b2b, out, NN);
}

// Round 12
// 210.525 us; speedup vs baseline: 1.6724x; 1.2334x over previous
//
#include <hip/hip_runtime.h>

#define NN 50000
#define NE 600000
#define SCAN_BLOCKS 196  // 196*256 = 50176 >= NN

typedef short v8s __attribute__((ext_vector_type(8)));
typedef float v4f __attribute__((ext_vector_type(4)));

#define LAW 72    // lA row stride in shorts: 64 data + 8 pad
#define MTW 264   // mT row stride in shorts: 256 data + 8 pad

__device__ __forceinline__ float b2f(ushort u) {
    union { unsigned u; float f; } v; v.u = ((unsigned)u) << 16; return v.f;
}
__device__ __forceinline__ ushort f2b(float f) {
    union { float f; unsigned u; } v; v.f = f;
    unsigned r = v.u + 0x7FFFu + ((v.u >> 16) & 1u);  // RNE
    return (ushort)(r >> 16);
}

// ---------- edge-index dtype detection (int32 vs int64 storage) ----------
__global__ __launch_bounds__(256) void detect_idx_kernel(const int* __restrict__ raw,
                                                          int* __restrict__ flag) {
    __shared__ int cnt;
    if (threadIdx.x == 0) cnt = 0;
    __syncthreads();
    int c = 0;
    for (int i = threadIdx.x; i < 2048; i += 256)
        if (raw[2 * i + 1] != 0) c++;
    atomicAdd(&cnt, c);
    __syncthreads();
    if (threadIdx.x == 0) *flag = (cnt > 10) ? 1 : 0;  // 1 => int32 layout
}

// convert + fused degree count (dst half feeds deg atomics)
__global__ __launch_bounds__(256) void convert_idx_kernel(const void* __restrict__ raw,
                                                           const int* __restrict__ flag,
                                                           int* __restrict__ out,
                                                           int* __restrict__ deg, int n) {
    int i = blockIdx.x * 256 + threadIdx.x;
    if (i >= n) return;
    int v;
    if (*flag) v = ((const int*)raw)[i];
    else       v = (int)((const long long*)raw)[i];
    out[i] = v;
    if (i >= NE) atomicAdd(&deg[v], 1);  // dst half
}

// ---------- hierarchical scan: deg[NN] -> rowptr[NN+1], cursor[NN] ----------
__global__ __launch_bounds__(256) void block_sum_kernel(const int* __restrict__ deg,
                                                         int* __restrict__ bsum) {
    const int i = blockIdx.x * 256 + threadIdx.x;
    int v = (i < NN) ? deg[i] : 0;
#pragma unroll
    for (int o = 32; o; o >>= 1) v += __shfl_down(v, o, 64);
    __shared__ int ws[4];
    if ((threadIdx.x & 63) == 0) ws[threadIdx.x >> 6] = v;
    __syncthreads();
    if (threadIdx.x == 0) bsum[blockIdx.x] = ws[0] + ws[1] + ws[2] + ws[3];
}

__global__ __launch_bounds__(256) void scan_sums_kernel(const int* __restrict__ bsum,
                                                         int* __restrict__ boff,
                                                         int* __restrict__ rowptr) {
    __shared__ int tmp[256];
    const int t = threadIdx.x;
    const int v = (t < SCAN_BLOCKS) ? bsum[t] : 0;
    tmp[t] = v;
    __syncthreads();
#pragma unroll
    for (int off = 1; off < 256; off <<= 1) {
        int u = (t >= off) ? tmp[t - off] : 0;
        __syncthreads();
        tmp[t] += u;
        __syncthreads();
    }
    boff[t] = tmp[t] - v;  // exclusive
    if (t == 255) rowptr[NN] = tmp[255];
}

__global__ __launch_bounds__(256) void block_scan_kernel(const int* __restrict__ deg,
                                                          const int* __restrict__ boff,
                                                          int* __restrict__ rowptr,
                                                          int* __restrict__ cursor) {
    const int t = threadIdx.x;
    const int i = blockIdx.x * 256 + t;
    const int lane = t & 63, w = t >> 6;
    const int v = (i < NN) ? deg[i] : 0;
    int s = v;
#pragma unroll
    for (int o = 1; o < 64; o <<= 1) {
        int u = __shfl_up(s, o, 64);
        if (lane >= o) s += u;
    }
    __shared__ int wsum[4];
    if (lane == 63) wsum[w] = s;
    __syncthreads();
    int wpre = 0;
    for (int k = 0; k < w; k++) wpre += wsum[k];
    const int excl = boff[blockIdx.x] + wpre + s - v;
    if (i < NN) {
        rowptr[i] = excl;
        cursor[i] = excl;
    }
}

__global__ __launch_bounds__(256) void fill_csr_kernel(const int* __restrict__ srcIdx,
                                                        const int* __restrict__ dstIdx,
                                                        int* __restrict__ cursor,
                                                        int* __restrict__ csr_src) {
    int e = blockIdx.x * 256 + threadIdx.x;
    if (e >= NE) return;
    int pos = atomicAdd(&cursor[dstIdx[e]], 1);
    csr_src[pos] = srcIdx[e];
}

// ---------- fp32 -> bf16 converter ----------
__global__ __launch_bounds__(256) void cvt_f32_bf16_kernel(const float* __restrict__ in,
                                                            ushort* __restrict__ out, int n4) {
    int i = blockIdx.x * 256 + threadIdx.x;
    if (i >= n4) return;
    const float4 v = *(const float4*)&in[(size_t)i * 4];
    ushort4 o;
    o.x = f2b(v.x); o.y = f2b(v.y); o.z = f2b(v.z); o.w = f2b(v.w);
    *(ushort4*)&out[(size_t)i * 4] = o;
}

// ---------- fragment-major weight packing ----------
// Stage-1 W1 [K1][256] fp32 -> frag-major bf16. Frag id f = s*32 + wv*8 + n*2 + kk;
// within frag: lane*8 + j. k = s*64+kk*32+(lane>>4)*8+j; col = wv*64+n*16+(lane&15).
__global__ __launch_bounds__(256) void pack_w1_kernel(const float* __restrict__ in,
                                                       ushort* __restrict__ out, int K1) {
    int o = blockIdx.x * 256 + threadIdx.x;
    if (o >= K1 * 256) return;
    int j = o & 7, lane = (o >> 3) & 63, f = o >> 9;
    int kk = f & 1, n = (f >> 1) & 3, wv = (f >> 3) & 3, s = f >> 5;
    int k = s * 64 + kk * 32 + (lane >> 4) * 8 + j;
    int col = wv * 64 + n * 16 + (lane & 15);
    out[o] = f2b(in[(size_t)k * 256 + col]);
}

// Stage-2 W2 [256][256] fp32 -> frag-major. f = kh*64 + wv*16 + n*4 + kk.
__global__ __launch_bounds__(256) void pack_w2_kernel(const float* __restrict__ in,
                                                       ushort* __restrict__ out) {
    int o = blockIdx.x * 256 + threadIdx.x;
    if (o >= 256 * 256) return;
    int j = o & 7, lane = (o >> 3) & 63, f = o >> 9;
    int kk = f & 3, n = (f >> 2) & 3, wv = (f >> 4) & 3, kh = f >> 6;
    int k = kh * 128 + kk * 32 + (lane >> 4) * 8 + j;
    int col = wv * 64 + n * 16 + (lane & 15);
    out[o] = f2b(in[(size_t)k * 256 + col]);
}

// Head W2b [256][16] fp32 -> frag-major. f = k8 (0..7).
__global__ __launch_bounds__(256) void pack_wh_kernel(const float* __restrict__ in,
                                                       ushort* __restrict__ out) {
    int o = blockIdx.x * 256 + threadIdx.x;
    if (o >= 4096) return;
    int j = o & 7, lane = (o >> 3) & 63, k8 = o >> 9;
    int k = k8 * 32 + (lane >> 4) * 8 + j;
    int col = lane & 15;
    out[o] = f2b(in[(size_t)k * 16 + col]);
}

// ---------- gather-aggregate (bf16 in/out, fp32 accum) ----------
template <int D>
__global__ __launch_bounds__(256) void aggregate_bf16_kernel(const ushort* __restrict__ feat,
                                                              ushort* __restrict__ z,
                                                              const int* __restrict__ rowptr,
                                                              const int* __restrict__ csr_src) {
    const int node = blockIdx.x * 4 + (threadIdx.x >> 6);
    const int lane = threadIdx.x & 63;
    if (node >= NN) return;
    const int rbeg = rowptr[node];
    const int rend = rowptr[node + 1];

    if (D == 256) {
        const size_t base = (size_t)node * 256 + lane * 4;
        uint2 sv = *(const uint2*)&feat[base];
        float a0 = b2f((ushort)sv.x), a1 = b2f((ushort)(sv.x >> 16));
        float a2 = b2f((ushort)sv.y), a3 = b2f((ushort)(sv.y >> 16));
        int j = rbeg;
        for (; j + 3 < rend; j += 4) {
            const int s0 = csr_src[j], s1 = csr_src[j + 1];
            const int s2 = csr_src[j + 2], s3 = csr_src[j + 3];
            const uint2 v0 = *(const uint2*)&feat[(size_t)s0 * 256 + lane * 4];
            const uint2 v1 = *(const uint2*)&feat[(size_t)s1 * 256 + lane * 4];
            const uint2 v2 = *(const uint2*)&feat[(size_t)s2 * 256 + lane * 4];
            const uint2 v3 = *(const uint2*)&feat[(size_t)s3 * 256 + lane * 4];
            a0 += b2f((ushort)v0.x) + b2f((ushort)v1.x) + b2f((ushort)v2.x) + b2f((ushort)v3.x);
            a1 += b2f((ushort)(v0.x >> 16)) + b2f((ushort)(v1.x >> 16)) + b2f((ushort)(v2.x >> 16)) + b2f((ushort)(v3.x >> 16));
            a2 += b2f((ushort)v0.y) + b2f((ushort)v1.y) + b2f((ushort)v2.y) + b2f((ushort)v3.y);
            a3 += b2f((ushort)(v0.y >> 16)) + b2f((ushort)(v1.y >> 16)) + b2f((ushort)(v2.y >> 16)) + b2f((ushort)(v3.y >> 16));
        }
        for (; j < rend; j++) {
            const uint2 v = *(const uint2*)&feat[(size_t)csr_src[j] * 256 + lane * 4];
            a0 += b2f((ushort)v.x); a1 += b2f((ushort)(v.x >> 16));
            a2 += b2f((ushort)v.y); a3 += b2f((ushort)(v.y >> 16));
        }
        uint2 o;
        o.x = (uint)f2b(a0) | ((uint)f2b(a1) << 16);
        o.y = (uint)f2b(a2) | ((uint)f2b(a3) << 16);
        *(uint2*)&z[base] = o;
    } else {  // D == 128
        const size_t base = (size_t)node * 128 + lane * 2;
        uint sv = *(const uint*)&feat[base];
        float a0 = b2f((ushort)sv), a1 = b2f((ushort)(sv >> 16));
        int j = rbeg;
        for (; j + 3 < rend; j += 4) {
            const int s0 = csr_src[j], s1 = csr_src[j + 1];
            const int s2 = csr_src[j + 2], s3 = csr_src[j + 3];
            const uint v0 = *(const uint*)&feat[(size_t)s0 * 128 + lane * 2];
            const uint v1 = *(const uint*)&feat[(size_t)s1 * 128 + lane * 2];
            const uint v2 = *(const uint*)&feat[(size_t)s2 * 128 + lane * 2];
            const uint v3 = *(const uint*)&feat[(size_t)s3 * 128 + lane * 2];
            a0 += b2f((ushort)v0) + b2f((ushort)v1) + b2f((ushort)v2) + b2f((ushort)v3);
            a1 += b2f((ushort)(v0 >> 16)) + b2f((ushort)(v1 >> 16)) + b2f((ushort)(v2 >> 16)) + b2f((ushort)(v3 >> 16));
        }
        for (; j < rend; j++) {
            const uint v = *(const uint*)&feat[(size_t)csr_src[j] * 128 + lane * 2];
            a0 += b2f((ushort)v); a1 += b2f((ushort)(v >> 16));
        }
        *(uint*)&z[base] = (uint)f2b(a0) | ((uint)f2b(a1) << 16);
    }
}

// ---------- fused 2-layer MLP v5: round-9 structure + frag-major W + blit epilogue ----
// Block: 64 rows, 4 waves. All W loads are contiguous 1KB wave-bursts (lane*16B)
// from the packed layouts above. Stage 1: A via double-buffered LDS (BK=64),
// W1 frags register-prefetched one step ahead. Stage 2: barrier-free MFMA,
// result staged through mT and blitted with coalesced dwordx4 stores.
template <int K1, bool HEAD>
__global__ __launch_bounds__(256) void fused_mlp_kernel(const ushort* __restrict__ A,
                                                         const ushort* __restrict__ W1p,
                                                         const float* __restrict__ b1,
                                                         const ushort* __restrict__ W2p,
                                                         const float* __restrict__ b2,
                                                         void* __restrict__ outp, int M) {
    constexpr int S = K1 / 64;          // stage-1 k-steps
    __shared__ ushort lA[2][64 * LAW];  // 18.4 KB dbuf A k-tile [64][64]
    __shared__ ushort mT[64 * MTW];     // 33.8 KB stage-1 output [64][256] bf16
    const int tid = threadIdx.x;
    const int lane = tid & 63;
    const int wv = tid >> 6;
    const int row0 = blockIdx.x * 64;
    const int l15 = lane & 15;
    const int kq = lane >> 4;
    const int ar = tid >> 2, ak = (tid & 3) * 16;  // A staging: row, k-chunk

    const bool aok = (row0 + ar) < M;
    const ushort* Arow = A + (size_t)(row0 + ar) * K1 + ak;

    v4f acc[4][4];
#pragma unroll
    for (int m = 0; m < 4; m++)
#pragma unroll
        for (int n = 0; n < 4; n++) acc[m][n] = (v4f){0.f, 0.f, 0.f, 0.f};

    v8s a0 = {}, a1v = {};
    v8s w1cur[4][2], w1nxt[4][2];

    // ---- prologue: step-0 A + W1 (contiguous frag loads) ----
    if (aok) { a0 = *(const v8s*)Arow; a1v = *(const v8s*)(Arow + 8); }
#pragma unroll
    for (int n = 0; n < 4; n++)
#pragma unroll
        for (int kk = 0; kk < 2; kk++)
            w1cur[n][kk] = *(const v8s*)(W1p + (size_t)(wv * 8 + n * 2 + kk) * 512 + lane * 8);
    *(v8s*)&lA[0][ar * LAW + ak]     = a0;
    *(v8s*)&lA[0][ar * LAW + ak + 8] = a1v;

    // ---- stage 1: m = relu(A @ W1 + b1) ----
#pragma unroll
    for (int s = 0; s < S; s++) {
        __syncthreads();
        if (s + 1 < S) {
            a0 = (v8s){}; a1v = (v8s){};
            if (aok) {
                a0  = *(const v8s*)(Arow + (s + 1) * 64);
                a1v = *(const v8s*)(Arow + (s + 1) * 64 + 8);
            }
#pragma unroll
            for (int n = 0; n < 4; n++)
#pragma unroll
                for (int kk = 0; kk < 2; kk++)
                    w1nxt[n][kk] = *(const v8s*)(W1p + (size_t)((s + 1) * 32 + wv * 8 + n * 2 + kk) * 512 + lane * 8);
        }
        v8s af[4][2];
#pragma unroll
        for (int m = 0; m < 4; m++)
#pragma unroll
            for (int kk = 0; kk < 2; kk++)
                af[m][kk] = *(const v8s*)&lA[s & 1][(m * 16 + l15) * LAW + kk * 32 + kq * 8];
#pragma unroll
        for (int kk = 0; kk < 2; kk++)
#pragma unroll
            for (int m = 0; m < 4; m++)
#pragma unroll
                for (int n = 0; n < 4; n++)
                    acc[m][n] = __builtin_amdgcn_mfma_f32_16x16x32_bf16(af[m][kk], w1cur[n][kk], acc[m][n], 0, 0, 0);
        if (s + 1 < S) {
            *(v8s*)&lA[(s + 1) & 1][ar * LAW + ak]     = a0;
            *(v8s*)&lA[(s + 1) & 1][ar * LAW + ak + 8] = a1v;
#pragma unroll
            for (int n = 0; n < 4; n++)
#pragma unroll
                for (int kk = 0; kk < 2; kk++)
                    w1cur[n][kk] = w1nxt[n][kk];
        }
    }

    // ---- stage-1 epilogue: bias + relu -> mT (bf16) ----
#pragma unroll
    for (int n = 0; n < 4; n++) {
        const int gc = wv * 64 + n * 16 + l15;
        const float bv = b1[gc];
#pragma unroll
        for (int m = 0; m < 4; m++)
#pragma unroll
            for (int r = 0; r < 4; r++)
                mT[(m * 16 + kq * 4 + r) * MTW + gc] = f2b(fmaxf(acc[m][n][r] + bv, 0.f));
    }
    __syncthreads();  // mT ready

    if constexpr (!HEAD) {
        // ---- stage 2: C = relu(m @ W2 + b2), barrier-free MFMA ----
#pragma unroll
        for (int m = 0; m < 4; m++)
#pragma unroll
            for (int n = 0; n < 4; n++) acc[m][n] = (v4f){0.f, 0.f, 0.f, 0.f};
#pragma unroll
        for (int kh = 0; kh < 2; kh++) {
            v8s w2r[4][4];
#pragma unroll
            for (int n = 0; n < 4; n++)
#pragma unroll
                for (int kk = 0; kk < 4; kk++)
                    w2r[n][kk] = *(const v8s*)(W2p + (size_t)(kh * 64 + wv * 16 + n * 4 + kk) * 512 + lane * 8);
#pragma unroll
            for (int kk = 0; kk < 4; kk++) {
                v8s a2[4];
#pragma unroll
                for (int m = 0; m < 4; m++)
                    a2[m] = *(const v8s*)&mT[(m * 16 + l15) * MTW + kh * 128 + kk * 32 + kq * 8];
#pragma unroll
                for (int m = 0; m < 4; m++)
#pragma unroll
                    for (int n = 0; n < 4; n++)
                        acc[m][n] = __builtin_amdgcn_mfma_f32_16x16x32_bf16(a2[m], w2r[n][kk], acc[m][n], 0, 0, 0);
            }
        }
        __syncthreads();  // all mT reads done before overwrite
        // write result back into mT (bias+relu+bf16)
#pragma unroll
        for (int n = 0; n < 4; n++) {
            const int gc = wv * 64 + n * 16 + l15;
            const float bv = b2[gc];
#pragma unroll
            for (int m = 0; m < 4; m++)
#pragma unroll
                for (int r = 0; r < 4; r++)
                    mT[(m * 16 + kq * 4 + r) * MTW + gc] = f2b(fmaxf(acc[m][n][r] + bv, 0.f));
        }
        __syncthreads();
        // coalesced blit: chunk i covers rows i*8..i*8+7; thread t -> 16B at
        // row = i*8 + (t>>5), col = (t&31)*8  -> global contiguous 4KB per chunk
        ushort* C = (ushort*)outp;
        const int brow = tid >> 5, bcol = (tid & 31) * 8;
#pragma unroll
        for (int i = 0; i < 8; i++) {
            const int row = i * 8 + brow;
            if (row0 + row < M) {
                const v8s v = *(const v8s*)&mT[row * MTW + bcol];
                *(v8s*)&C[(size_t)(row0 + row) * 256 + bcol] = v;
            }
        }
    } else {
        // ---- stage 2 head: o = m @ W2b + b2 (16 cols), log_softmax, fp32 out ----
        // wave wv owns rows wv*16..+15; head frags shared by all waves (L2-hot)
        v4f h = (v4f){0.f, 0.f, 0.f, 0.f};
        v8s w2r[8];
#pragma unroll
        for (int k8 = 0; k8 < 8; k8++)
            w2r[k8] = *(const v8s*)(W2p + (size_t)k8 * 512 + lane * 8);
#pragma unroll
        for (int k8 = 0; k8 < 8; k8++) {
            const v8s a2 = *(const v8s*)&mT[(wv * 16 + l15) * MTW + k8 * 32 + kq * 8];
            h = __builtin_amdgcn_mfma_f32_16x16x32_bf16(a2, w2r[k8], h, 0, 0, 0);
        }
        float* O = (float*)outp;
        const float bv = b2[l15];
#pragma unroll
        for (int r = 0; r < 4; r++) {
            const float v = h[r] + bv;
            float mx = v;
#pragma unroll
            for (int o = 8; o; o >>= 1) mx = fmaxf(mx, __shfl_xor(mx, o, 16));
            const float e = expf(v - mx);
            float sl = e;
#pragma unroll
            for (int o = 8; o; o >>= 1) sl += __shfl_xor(sl, o, 16);
            const int grow = row0 + wv * 16 + kq * 4 + r;
            if (grow < M) O[(size_t)grow * 16 + l15] = (v - mx) - logf(sl);
        }
    }
}

extern "C" void kernel_launch(void* const* d_in, const int* in_sizes, int n_in,
                              void* d_out, int out_size, void* d_ws, size_t ws_size,
                              hipStream_t stream) {
    (void)in_sizes; (void)n_in; (void)out_size; (void)ws_size;
    const float* x   = (const float*)d_in[0];
    const void*  ei  = d_in[1];
    const float* w1a = (const float*)d_in[2];
    const float* b1a = (const float*)d_in[3];
    const float* w2a = (const float*)d_in[4];
    const float* b2a = (const float*)d_in[5];
    const float* w1b = (const float*)d_in[6];
    const float* b1b = (const float*)d_in[7];
    const float* w2b = (const float*)d_in[8];
    const float* b2b = (const float*)d_in[9];
    float* out = (float*)d_out;

    // ws layout (ushort region first, then ints)
    ushort* XB   = (ushort*)d_ws;                 // [NN][128] bf16: x
    ushort* Z1   = XB + (size_t)NN * 128;         // [NN][128] bf16: z1
    ushort* H1   = Z1 + (size_t)NN * 128;         // [NN][256] bf16: h1
    ushort* Z2   = H1 + (size_t)NN * 256;         // [NN][256] bf16: z2
    ushort* W1pa = Z2 + (size_t)NN * 256;         // 128*256 packed
    ushort* W2pa = W1pa + 128 * 256;              // 256*256 packed
    ushort* W1pb = W2pa + 256 * 256;              // 256*256 packed
    ushort* W2hp = W1pb + 256 * 256;              // 16*256 packed
    int* idx     = (int*)(W2hp + 16 * 256);       // 2*NE
    int* flag    = idx + 2 * NE;
    int* deg     = flag + 1;                      // NN
    int* rowptr  = deg + NN;                      // NN+1
    int* cursor  = rowptr + NN + 1;               // NN
    int* csr_src = cursor + NN;                   // NE
    int* bsum    = csr_src + NE;                  // SCAN_BLOCKS
    int* boff    = bsum + SCAN_BLOCKS;            // 256

    // ---- edge index normalize + CSR ----
    detect_idx_kernel<<<1, 256, 0, stream>>>((const int*)ei, flag);
    hipMemsetAsync(deg, 0, NN * sizeof(int), stream);
    convert_idx_kernel<<<(2 * NE + 255) / 256, 256, 0, stream>>>(ei, flag, idx, deg, 2 * NE);
    const int* srcI = idx;
    const int* dstI = idx + NE;
    block_sum_kernel<<<SCAN_BLOCKS, 256, 0, stream>>>(deg, bsum);
    scan_sums_kernel<<<1, 256, 0, stream>>>(bsum, boff, rowptr);
    block_scan_kernel<<<SCAN_BLOCKS, 256, 0, stream>>>(deg, boff, rowptr, cursor);
    fill_csr_kernel<<<(NE + 255) / 256, 256, 0, stream>>>(srcI, dstI, cursor, csr_src);

    // ---- bf16 conversions + fragment-major weight packing ----
    cvt_f32_bf16_kernel<<<(NN * 128 / 4 + 255) / 256, 256, 0, stream>>>(x, XB, NN * 128 / 4);
    pack_w1_kernel<<<(128 * 256 + 255) / 256, 256, 0, stream>>>(w1a, W1pa, 128);
    pack_w2_kernel<<<(256 * 256 + 255) / 256, 256, 0, stream>>>(w2a, W2pa);
    pack_w1_kernel<<<(256 * 256 + 255) / 256, 256, 0, stream>>>(w1b, W1pb, 256);
    pack_wh_kernel<<<(4096 + 255) / 256, 256, 0, stream>>>(w2b, W2hp);

    const int aggBlocks = (NN + 3) / 4;
    const int mlpBlocks = (NN + 63) / 64;

    // ---- conv1: aggregate + fused MLP (z1 -> h1) ----
    aggregate_bf16_kernel<128><<<aggBlocks, 256, 0, stream>>>(XB, Z1, rowptr, csr_src);
    fused_mlp_kernel<128, false><<<mlpBlocks, 256, 0, stream>>>(Z1, W1pa, b1a, W2pa, b2a, H1, NN);

    // ---- conv2: aggregate + fused MLP + head (z2 -> out) ----
    aggregate_bf16_kernel<256><<<aggBlocks, 256, 0, stream>>>(H1, Z2, rowptr, csr_src);
    fused_mlp_kernel<256, true><<<mlpBlocks, 256, 0, stream>>>(Z2, W1pb, b1b, W2hp, b2b, out, NN);
}

// Round 13
// 201.803 us; speedup vs baseline: 1.7447x; 1.0432x over previous
//
#include <hip/hip_runtime.h>

#define NN 50000
#define NE 600000
#define SCAN_BLOCKS 196  // 196*256 = 50176 >= NN

typedef short v8s __attribute__((ext_vector_type(8)));
typedef float v4f __attribute__((ext_vector_type(4)));

#define LAW 72    // lA row stride in shorts: 64 data + 8 pad
#define MTW 264   // mT row stride in shorts: 256 data + 8 pad

__device__ __forceinline__ float b2f(ushort u) {
    union { unsigned u; float f; } v; v.u = ((unsigned)u) << 16; return v.f;
}
__device__ __forceinline__ float uaf(unsigned u) {
    union { unsigned u; float f; } v; v.u = u; return v.f;
}
__device__ __forceinline__ ushort f2b(float f) {
    union { float f; unsigned u; } v; v.f = f;
    unsigned r = v.u + 0x7FFFu + ((v.u >> 16) & 1u);  // RNE
    return (ushort)(r >> 16);
}

// ---------- edge-index dtype detection (int32 vs int64 storage) ----------
__global__ __launch_bounds__(256) void detect_idx_kernel(const int* __restrict__ raw,
                                                          int* __restrict__ flag) {
    __shared__ int cnt;
    if (threadIdx.x == 0) cnt = 0;
    __syncthreads();
    int c = 0;
    for (int i = threadIdx.x; i < 2048; i += 256)
        if (raw[2 * i + 1] != 0) c++;
    atomicAdd(&cnt, c);
    __syncthreads();
    if (threadIdx.x == 0) *flag = (cnt > 10) ? 1 : 0;  // 1 => int32 layout
}

// convert + fused degree count (dst half feeds deg atomics)
__global__ __launch_bounds__(256) void convert_idx_kernel(const void* __restrict__ raw,
                                                           const int* __restrict__ flag,
                                                           int* __restrict__ out,
                                                           int* __restrict__ deg, int n) {
    int i = blockIdx.x * 256 + threadIdx.x;
    if (i >= n) return;
    int v;
    if (*flag) v = ((const int*)raw)[i];
    else       v = (int)((const long long*)raw)[i];
    out[i] = v;
    if (i >= NE) atomicAdd(&deg[v], 1);  // dst half
}

// ---------- hierarchical scan: deg[NN] -> rowptr[NN+1], cursor[NN] ----------
__global__ __launch_bounds__(256) void block_sum_kernel(const int* __restrict__ deg,
                                                         int* __restrict__ bsum) {
    const int i = blockIdx.x * 256 + threadIdx.x;
    int v = (i < NN) ? deg[i] : 0;
#pragma unroll
    for (int o = 32; o; o >>= 1) v += __shfl_down(v, o, 64);
    __shared__ int ws[4];
    if ((threadIdx.x & 63) == 0) ws[threadIdx.x >> 6] = v;
    __syncthreads();
    if (threadIdx.x == 0) bsum[blockIdx.x] = ws[0] + ws[1] + ws[2] + ws[3];
}

__global__ __launch_bounds__(256) void scan_sums_kernel(const int* __restrict__ bsum,
                                                         int* __restrict__ boff,
                                                         int* __restrict__ rowptr) {
    __shared__ int tmp[256];
    const int t = threadIdx.x;
    const int v = (t < SCAN_BLOCKS) ? bsum[t] : 0;
    tmp[t] = v;
    __syncthreads();
#pragma unroll
    for (int off = 1; off < 256; off <<= 1) {
        int u = (t >= off) ? tmp[t - off] : 0;
        __syncthreads();
        tmp[t] += u;
        __syncthreads();
    }
    boff[t] = tmp[t] - v;  // exclusive
    if (t == 255) rowptr[NN] = tmp[255];
}

__global__ __launch_bounds__(256) void block_scan_kernel(const int* __restrict__ deg,
                                                          const int* __restrict__ boff,
                                                          int* __restrict__ rowptr,
                                                          int* __restrict__ cursor) {
    const int t = threadIdx.x;
    const int i = blockIdx.x * 256 + t;
    const int lane = t & 63, w = t >> 6;
    const int v = (i < NN) ? deg[i] : 0;
    int s = v;
#pragma unroll
    for (int o = 1; o < 64; o <<= 1) {
        int u = __shfl_up(s, o, 64);
        if (lane >= o) s += u;
    }
    __shared__ int wsum[4];
    if (lane == 63) wsum[w] = s;
    __syncthreads();
    int wpre = 0;
    for (int k = 0; k < w; k++) wpre += wsum[k];
    const int excl = boff[blockIdx.x] + wpre + s - v;
    if (i < NN) {
        rowptr[i] = excl;
        cursor[i] = excl;
    }
}

__global__ __launch_bounds__(256) void fill_csr_kernel(const int* __restrict__ srcIdx,
                                                        const int* __restrict__ dstIdx,
                                                        int* __restrict__ cursor,
                                                        int* __restrict__ csr_src) {
    int e = blockIdx.x * 256 + threadIdx.x;
    if (e >= NE) return;
    int pos = atomicAdd(&cursor[dstIdx[e]], 1);
    csr_src[pos] = srcIdx[e];
}

// ---------- fp32 -> bf16 converter ----------
__global__ __launch_bounds__(256) void cvt_f32_bf16_kernel(const float* __restrict__ in,
                                                            ushort* __restrict__ out, int n4) {
    int i = blockIdx.x * 256 + threadIdx.x;
    if (i >= n4) return;
    const float4 v = *(const float4*)&in[(size_t)i * 4];
    ushort4 o;
    o.x = f2b(v.x); o.y = f2b(v.y); o.z = f2b(v.z); o.w = f2b(v.w);
    *(ushort4*)&out[(size_t)i * 4] = o;
}

// ---------- fragment-major weight packing ----------
// Stage-1 W1 [K1][256] fp32 -> frag-major bf16. Frag id f = s*32 + wv*8 + n*2 + kk;
// within frag: lane*8 + j. k = s*64+kk*32+(lane>>4)*8+j; col = wv*64+n*16+(lane&15).
__global__ __launch_bounds__(256) void pack_w1_kernel(const float* __restrict__ in,
                                                       ushort* __restrict__ out, int K1) {
    int o = blockIdx.x * 256 + threadIdx.x;
    if (o >= K1 * 256) return;
    int j = o & 7, lane = (o >> 3) & 63, f = o >> 9;
    int kk = f & 1, n = (f >> 1) & 3, wv = (f >> 3) & 3, s = f >> 5;
    int k = s * 64 + kk * 32 + (lane >> 4) * 8 + j;
    int col = wv * 64 + n * 16 + (lane & 15);
    out[o] = f2b(in[(size_t)k * 256 + col]);
}

// Stage-2 W2 [256][256] fp32 -> frag-major. f = kh*64 + wv*16 + n*4 + kk.
__global__ __launch_bounds__(256) void pack_w2_kernel(const float* __restrict__ in,
                                                       ushort* __restrict__ out) {
    int o = blockIdx.x * 256 + threadIdx.x;
    if (o >= 256 * 256) return;
    int j = o & 7, lane = (o >> 3) & 63, f = o >> 9;
    int kk = f & 3, n = (f >> 2) & 3, wv = (f >> 4) & 3, kh = f >> 6;
    int k = kh * 128 + kk * 32 + (lane >> 4) * 8 + j;
    int col = wv * 64 + n * 16 + (lane & 15);
    out[o] = f2b(in[(size_t)k * 256 + col]);
}

// Head W2b [256][16] fp32 -> frag-major. f = k8 (0..7).
__global__ __launch_bounds__(256) void pack_wh_kernel(const float* __restrict__ in,
                                                       ushort* __restrict__ out) {
    int o = blockIdx.x * 256 + threadIdx.x;
    if (o >= 4096) return;
    int j = o & 7, lane = (o >> 3) & 63, k8 = o >> 9;
    int k = k8 * 32 + (lane >> 4) * 8 + j;
    int col = lane & 15;
    out[o] = f2b(in[(size_t)k * 16 + col]);
}

// ---------- gather-aggregate v2: scalar index path, 8 gathers in flight ----------
template <int D>
__global__ __launch_bounds__(256) void aggregate_bf16_kernel(const ushort* __restrict__ feat,
                                                              ushort* __restrict__ z,
                                                              const int* __restrict__ rowptr,
                                                              const int* __restrict__ csr_src) {
    const int node = __builtin_amdgcn_readfirstlane(blockIdx.x * 4 + (threadIdx.x >> 6));
    const int lane = threadIdx.x & 63;
    if (node >= NN) return;
    const int rbeg = rowptr[node];
    const int rend = rowptr[node + 1];

    if constexpr (D == 256) {
        const size_t base = (size_t)node * 256 + lane * 4;
        const uint2 sv = *(const uint2*)&feat[base];
        float a0 = uaf(sv.x << 16), a1 = uaf(sv.x & 0xFFFF0000u);
        float a2 = uaf(sv.y << 16), a3 = uaf(sv.y & 0xFFFF0000u);
        int j = rbeg;
        for (; j + 7 < rend; j += 8) {
            uint2 v[8];
#pragma unroll
            for (int q = 0; q < 8; q++)
                v[q] = *(const uint2*)&feat[(size_t)csr_src[j + q] * 256 + lane * 4];
#pragma unroll
            for (int q = 0; q < 8; q++) {
                a0 += uaf(v[q].x << 16); a1 += uaf(v[q].x & 0xFFFF0000u);
                a2 += uaf(v[q].y << 16); a3 += uaf(v[q].y & 0xFFFF0000u);
            }
        }
        for (; j + 3 < rend; j += 4) {
            uint2 v[4];
#pragma unroll
            for (int q = 0; q < 4; q++)
                v[q] = *(const uint2*)&feat[(size_t)csr_src[j + q] * 256 + lane * 4];
#pragma unroll
            for (int q = 0; q < 4; q++) {
                a0 += uaf(v[q].x << 16); a1 += uaf(v[q].x & 0xFFFF0000u);
                a2 += uaf(v[q].y << 16); a3 += uaf(v[q].y & 0xFFFF0000u);
            }
        }
        for (; j < rend; j++) {
            const uint2 v = *(const uint2*)&feat[(size_t)csr_src[j] * 256 + lane * 4];
            a0 += uaf(v.x << 16); a1 += uaf(v.x & 0xFFFF0000u);
            a2 += uaf(v.y << 16); a3 += uaf(v.y & 0xFFFF0000u);
        }
        uint2 o;
        o.x = (uint)f2b(a0) | ((uint)f2b(a1) << 16);
        o.y = (uint)f2b(a2) | ((uint)f2b(a3) << 16);
        *(uint2*)&z[base] = o;
    } else {  // D == 128
        const size_t base = (size_t)node * 128 + lane * 2;
        const uint sv = *(const uint*)&feat[base];
        float a0 = uaf(sv << 16), a1 = uaf(sv & 0xFFFF0000u);
        int j = rbeg;
        for (; j + 7 < rend; j += 8) {
            uint v[8];
#pragma unroll
            for (int q = 0; q < 8; q++)
                v[q] = *(const uint*)&feat[(size_t)csr_src[j + q] * 128 + lane * 2];
#pragma unroll
            for (int q = 0; q < 8; q++) {
                a0 += uaf(v[q] << 16); a1 += uaf(v[q] & 0xFFFF0000u);
            }
        }
        for (; j + 3 < rend; j += 4) {
            uint v[4];
#pragma unroll
            for (int q = 0; q < 4; q++)
                v[q] = *(const uint*)&feat[(size_t)csr_src[j + q] * 128 + lane * 2];
#pragma unroll
            for (int q = 0; q < 4; q++) {
                a0 += uaf(v[q] << 16); a1 += uaf(v[q] & 0xFFFF0000u);
            }
        }
        for (; j < rend; j++) {
            const uint v = *(const uint*)&feat[(size_t)csr_src[j] * 128 + lane * 2];
            a0 += uaf(v << 16); a1 += uaf(v & 0xFFFF0000u);
        }
        *(uint*)&z[base] = (uint)f2b(a0) | ((uint)f2b(a1) << 16);
    }
}

// ---------- fused 2-layer MLP v5: frag-major W + blit epilogue (round-12, best) ----
template <int K1, bool HEAD>
__global__ __launch_bounds__(256) void fused_mlp_kernel(const ushort* __restrict__ A,
                                                         const ushort* __restrict__ W1p,
                                                         const float* __restrict__ b1,
                                                         const ushort* __restrict__ W2p,
                                                         const float* __restrict__ b2,
                                                         void* __restrict__ outp, int M) {
    constexpr int S = K1 / 64;          // stage-1 k-steps
    __shared__ ushort lA[2][64 * LAW];  // 18.4 KB dbuf A k-tile [64][64]
    __shared__ ushort mT[64 * MTW];     // 33.8 KB stage-1 output [64][256] bf16
    const int tid = threadIdx.x;
    const int lane = tid & 63;
    const int wv = tid >> 6;
    const int row0 = blockIdx.x * 64;
    const int l15 = lane & 15;
    const int kq = lane >> 4;
    const int ar = tid >> 2, ak = (tid & 3) * 16;  // A staging: row, k-chunk

    const bool aok = (row0 + ar) < M;
    const ushort* Arow = A + (size_t)(row0 + ar) * K1 + ak;

    v4f acc[4][4];
#pragma unroll
    for (int m = 0; m < 4; m++)
#pragma unroll
        for (int n = 0; n < 4; n++) acc[m][n] = (v4f){0.f, 0.f, 0.f, 0.f};

    v8s a0 = {}, a1v = {};
    v8s w1cur[4][2], w1nxt[4][2];

    // ---- prologue: step-0 A + W1 (contiguous frag loads) ----
    if (aok) { a0 = *(const v8s*)Arow; a1v = *(const v8s*)(Arow + 8); }
#pragma unroll
    for (int n = 0; n < 4; n++)
#pragma unroll
        for (int kk = 0; kk < 2; kk++)
            w1cur[n][kk] = *(const v8s*)(W1p + (size_t)(wv * 8 + n * 2 + kk) * 512 + lane * 8);
    *(v8s*)&lA[0][ar * LAW + ak]     = a0;
    *(v8s*)&lA[0][ar * LAW + ak + 8] = a1v;

    // ---- stage 1: m = relu(A @ W1 + b1) ----
#pragma unroll
    for (int s = 0; s < S; s++) {
        __syncthreads();
        if (s + 1 < S) {
            a0 = (v8s){}; a1v = (v8s){};
            if (aok) {
                a0  = *(const v8s*)(Arow + (s + 1) * 64);
                a1v = *(const v8s*)(Arow + (s + 1) * 64 + 8);
            }
#pragma unroll
            for (int n = 0; n < 4; n++)
#pragma unroll
                for (int kk = 0; kk < 2; kk++)
                    w1nxt[n][kk] = *(const v8s*)(W1p + (size_t)((s + 1) * 32 + wv * 8 + n * 2 + kk) * 512 + lane * 8);
        }
        v8s af[4][2];
#pragma unroll
        for (int m = 0; m < 4; m++)
#pragma unroll
            for (int kk = 0; kk < 2; kk++)
                af[m][kk] = *(const v8s*)&lA[s & 1][(m * 16 + l15) * LAW + kk * 32 + kq * 8];
#pragma unroll
        for (int kk = 0; kk < 2; kk++)
#pragma unroll
            for (int m = 0; m < 4; m++)
#pragma unroll
                for (int n = 0; n < 4; n++)
                    acc[m][n] = __builtin_amdgcn_mfma_f32_16x16x32_bf16(af[m][kk], w1cur[n][kk], acc[m][n], 0, 0, 0);
        if (s + 1 < S) {
            *(v8s*)&lA[(s + 1) & 1][ar * LAW + ak]     = a0;
            *(v8s*)&lA[(s + 1) & 1][ar * LAW + ak + 8] = a1v;
#pragma unroll
            for (int n = 0; n < 4; n++)
#pragma unroll
                for (int kk = 0; kk < 2; kk++)
                    w1cur[n][kk] = w1nxt[n][kk];
        }
    }

    // ---- stage-1 epilogue: bias + relu -> mT (bf16) ----
#pragma unroll
    for (int n = 0; n < 4; n++) {
        const int gc = wv * 64 + n * 16 + l15;
        const float bv = b1[gc];
#pragma unroll
        for (int m = 0; m < 4; m++)
#pragma unroll
            for (int r = 0; r < 4; r++)
                mT[(m * 16 + kq * 4 + r) * MTW + gc] = f2b(fmaxf(acc[m][n][r] + bv, 0.f));
    }
    __syncthreads();  // mT ready

    if constexpr (!HEAD) {
        // ---- stage 2: C = relu(m @ W2 + b2), barrier-free MFMA ----
#pragma unroll
        for (int m = 0; m < 4; m++)
#pragma unroll
            for (int n = 0; n < 4; n++) acc[m][n] = (v4f){0.f, 0.f, 0.f, 0.f};
#pragma unroll
        for (int kh = 0; kh < 2; kh++) {
            v8s w2r[4][4];
#pragma unroll
            for (int n = 0; n < 4; n++)
#pragma unroll
                for (int kk = 0; kk < 4; kk++)
                    w2r[n][kk] = *(const v8s*)(W2p + (size_t)(kh * 64 + wv * 16 + n * 4 + kk) * 512 + lane * 8);
#pragma unroll
            for (int kk = 0; kk < 4; kk++) {
                v8s a2[4];
#pragma unroll
                for (int m = 0; m < 4; m++)
                    a2[m] = *(const v8s*)&mT[(m * 16 + l15) * MTW + kh * 128 + kk * 32 + kq * 8];
#pragma unroll
                for (int m = 0; m < 4; m++)
#pragma unroll
                    for (int n = 0; n < 4; n++)
                        acc[m][n] = __builtin_amdgcn_mfma_f32_16x16x32_bf16(a2[m], w2r[n][kk], acc[m][n], 0, 0, 0);
            }
        }
        __syncthreads();  // all mT reads done before overwrite
        // write result back into mT (bias+relu+bf16)
#pragma unroll
        for (int n = 0; n < 4; n++) {
            const int gc = wv * 64 + n * 16 + l15;
            const float bv = b2[gc];
#pragma unroll
            for (int m = 0; m < 4; m++)
#pragma unroll
                for (int r = 0; r < 4; r++)
                    mT[(m * 16 + kq * 4 + r) * MTW + gc] = f2b(fmaxf(acc[m][n][r] + bv, 0.f));
        }
        __syncthreads();
        // coalesced blit: chunk i covers rows i*8..i*8+7; thread t -> 16B at
        // row = i*8 + (t>>5), col = (t&31)*8  -> global contiguous 4KB per chunk
        ushort* C = (ushort*)outp;
        const int brow = tid >> 5, bcol = (tid & 31) * 8;
#pragma unroll
        for (int i = 0; i < 8; i++) {
            const int row = i * 8 + brow;
            if (row0 + row < M) {
                const v8s v = *(const v8s*)&mT[row * MTW + bcol];
                *(v8s*)&C[(size_t)(row0 + row) * 256 + bcol] = v;
            }
        }
    } else {
        // ---- stage 2 head: o = m @ W2b + b2 (16 cols), log_softmax, fp32 out ----
        v4f h = (v4f){0.f, 0.f, 0.f, 0.f};
        v8s w2r[8];
#pragma unroll
        for (int k8 = 0; k8 < 8; k8++)
            w2r[k8] = *(const v8s*)(W2p + (size_t)k8 * 512 + lane * 8);
#pragma unroll
        for (int k8 = 0; k8 < 8; k8++) {
            const v8s a2 = *(const v8s*)&mT[(wv * 16 + l15) * MTW + k8 * 32 + kq * 8];
            h = __builtin_amdgcn_mfma_f32_16x16x32_bf16(a2, w2r[k8], h, 0, 0, 0);
        }
        float* O = (float*)outp;
        const float bv = b2[l15];
#pragma unroll
        for (int r = 0; r < 4; r++) {
            const float v = h[r] + bv;
            float mx = v;
#pragma unroll
            for (int o = 8; o; o >>= 1) mx = fmaxf(mx, __shfl_xor(mx, o, 16));
            const float e = expf(v - mx);
            float sl = e;
#pragma unroll
            for (int o = 8; o; o >>= 1) sl += __shfl_xor(sl, o, 16);
            const int grow = row0 + wv * 16 + kq * 4 + r;
            if (grow < M) O[(size_t)grow * 16 + l15] = (v - mx) - logf(sl);
        }
    }
}

extern "C" void kernel_launch(void* const* d_in, const int* in_sizes, int n_in,
                              void* d_out, int out_size, void* d_ws, size_t ws_size,
                              hipStream_t stream) {
    (void)in_sizes; (void)n_in; (void)out_size; (void)ws_size;
    const float* x   = (const float*)d_in[0];
    const void*  ei  = d_in[1];
    const float* w1a = (const float*)d_in[2];
    const float* b1a = (const float*)d_in[3];
    const float* w2a = (const float*)d_in[4];
    const float* b2a = (const float*)d_in[5];
    const float* w1b = (const float*)d_in[6];
    const float* b1b = (const float*)d_in[7];
    const float* w2b = (const float*)d_in[8];
    const float* b2b = (const float*)d_in[9];
    float* out = (float*)d_out;

    // ws layout (ushort region first, then ints)
    ushort* XB   = (ushort*)d_ws;                 // [NN][128] bf16: x
    ushort* Z1   = XB + (size_t)NN * 128;         // [NN][128] bf16: z1
    ushort* H1   = Z1 + (size_t)NN * 128;         // [NN][256] bf16: h1
    ushort* Z2   = H1 + (size_t)NN * 256;         // [NN][256] bf16: z2
    ushort* W1pa = Z2 + (size_t)NN * 256;         // 128*256 packed
    ushort* W2pa = W1pa + 128 * 256;              // 256*256 packed
    ushort* W1pb = W2pa + 256 * 256;              // 256*256 packed
    ushort* W2hp = W1pb + 256 * 256;              // 16*256 packed
    int* idx     = (int*)(W2hp + 16 * 256);       // 2*NE
    int* flag    = idx + 2 * NE;
    int* deg     = flag + 1;                      // NN
    int* rowptr  = deg + NN;                      // NN+1
    int* cursor  = rowptr + NN + 1;               // NN
    int* csr_src = cursor + NN;                   // NE
    int* bsum    = csr_src + NE;                  // SCAN_BLOCKS
    int* boff    = bsum + SCAN_BLOCKS;            // 256

    // ---- edge index normalize + CSR ----
    detect_idx_kernel<<<1, 256, 0, stream>>>((const int*)ei, flag);
    hipMemsetAsync(deg, 0, NN * sizeof(int), stream);
    convert_idx_kernel<<<(2 * NE + 255) / 256, 256, 0, stream>>>(ei, flag, idx, deg, 2 * NE);
    const int* srcI = idx;
    const int* dstI = idx + NE;
    block_sum_kernel<<<SCAN_BLOCKS, 256, 0, stream>>>(deg, bsum);
    scan_sums_kernel<<<1, 256, 0, stream>>>(bsum, boff, rowptr);
    block_scan_kernel<<<SCAN_BLOCKS, 256, 0, stream>>>(deg, boff, rowptr, cursor);
    fill_csr_kernel<<<(NE + 255) / 256, 256, 0, stream>>>(srcI, dstI, cursor, csr_src);

    // ---- bf16 conversions + fragment-major weight packing ----
    cvt_f32_bf16_kernel<<<(NN * 128 / 4 + 255) / 256, 256, 0, stream>>>(x, XB, NN * 128 / 4);
    pack_w1_kernel<<<(128 * 256 + 255) / 256, 256, 0, stream>>>(w1a, W1pa, 128);
    pack_w2_kernel<<<(256 * 256 + 255) / 256, 256, 0, stream>>>(w2a, W2pa);
    pack_w1_kernel<<<(256 * 256 + 255) / 256, 256, 0, stream>>>(w1b, W1pb, 256);
    pack_wh_kernel<<<(4096 + 255) / 256, 256, 0, stream>>>(w2b, W2hp);

    const int aggBlocks = (NN + 3) / 4;
    const int mlpBlocks = (NN + 63) / 64;

    // ---- conv1: aggregate + fused MLP (z1 -> h1) ----
    aggregate_bf16_kernel<128><<<aggBlocks, 256, 0, stream>>>(XB, Z1, rowptr, csr_src);
    fused_mlp_kernel<128, false><<<mlpBlocks, 256, 0, stream>>>(Z1, W1pa, b1a, W2pa, b2a, H1, NN);

    // ---- conv2: aggregate + fused MLP + head (z2 -> out) ----
    aggregate_bf16_kernel<256><<<aggBlocks, 256, 0, stream>>>(H1, Z2, rowptr, csr_src);
    fused_mlp_kernel<256, true><<<mlpBlocks, 256, 0, stream>>>(Z2, W1pb, b1b, W2hp, b2b, out, NN);
}